// Round 7
// baseline (68.812 us; speedup 1.0000x reference)
//
#include <hip/hip_runtime.h>

#define NUM_CLASSES 26
#define NBINS (NUM_CLASSES * NUM_CLASSES)   // 676 pair bins
#define SUBS 2                              // LDS sub-histograms (sub-major layout)
#define LDSN (SUBS * NBINS)                 // 1352 words = 5.4 KB
#define NCOUNT (3 * NUM_CLASSES)            // 78 logical counters
#define TPB 256

// ---------- shared inner loop ----------
// One ds_atomic per ELEMENT: pair bin idx = a*26 + b.
// F[c] = row sum, M[c] = col sum, I[c] = diagonal.
#define PROC_PAIR(aa, bb)                                                    \
    do {                                                                     \
        atomicAdd(&h[hb + ((aa).x * NUM_CLASSES + (bb).x)], 1u);             \
        atomicAdd(&h[hb + ((aa).y * NUM_CLASSES + (bb).y)], 1u);             \
        atomicAdd(&h[hb + ((aa).z * NUM_CLASSES + (bb).z)], 1u);             \
        atomicAdd(&h[hb + ((aa).w * NUM_CLASSES + (bb).w)], 1u);             \
    } while (0)

#define HIST_BODY                                                            \
    __shared__ unsigned int h[LDSN];                                         \
    for (int i = threadIdx.x; i < LDSN; i += TPB) h[i] = 0u;                 \
    __syncthreads();                                                         \
    const int tid      = blockIdx.x * TPB + threadIdx.x;                     \
    const int nthreads = gridDim.x * TPB;                                    \
    const int hb       = (threadIdx.x & (SUBS - 1)) * NBINS;                 \
    for (int base = tid; base < nfull; base += nthreads * 8) {               \
        int4 a[8], b[8];                                                     \
        _Pragma("unroll")                                                    \
        for (int k = 0; k < 8; ++k) a[k] = f4[base + k * nthreads];          \
        _Pragma("unroll")                                                    \
        for (int k = 0; k < 8; ++k) b[k] = m4[base + k * nthreads];          \
        _Pragma("unroll")                                                    \
        for (int k = 0; k < 8; ++k) {                                        \
            int4 aa = a[k], bb = b[k];                                       \
            PROC_PAIR(aa, bb);                                               \
        }                                                                    \
    }                                                                        \
    for (int i = nfull + tid; i < n4; i += nthreads) {                       \
        int4 aa = f4[i], bb = m4[i];                                         \
        PROC_PAIR(aa, bb);                                                   \
    }                                                                        \
    __syncthreads();

// ---------- main path: non-atomic per-block partials, 2 dispatches ----------
// partials layout: counter-major [78][nblk]; every word written unconditionally
// every call -> no zero pass needed, no RMW contention.
__global__ __launch_bounds__(TPB, 2) void sdl_hist_p(
    const int4* __restrict__ f4, const int4* __restrict__ m4,
    unsigned int* __restrict__ partials, int nblk, int n4, int nfull) {
    HIST_BODY

    const int t = threadIdx.x;
    const int b = blockIdx.x;
    if (t < NUM_CLASSES) {                         // wave 0: F[c] = row sum
        unsigned int v = 0;
        #pragma unroll
        for (int j = 0; j < NUM_CLASSES; ++j)
            v += h[t * NUM_CLASSES + j] + h[NBINS + t * NUM_CLASSES + j];
        partials[t * nblk + b] = v;
    } else if (t >= 64 && t < 64 + NUM_CLASSES) {  // wave 1: M[c] = col sum
        int c = t - 64;
        unsigned int v = 0;
        #pragma unroll
        for (int j = 0; j < NUM_CLASSES; ++j)
            v += h[j * NUM_CLASSES + c] + h[NBINS + j * NUM_CLASSES + c];
        partials[(NUM_CLASSES + c) * nblk + b] = v;
    } else if (t >= 128 && t < 128 + NUM_CLASSES) {  // wave 2: I[c] = diagonal
        int c = t - 128;
        partials[(2 * NUM_CLASSES + c) * nblk + b] =
            h[c * NUM_CLASSES + c] + h[NBINS + c * NUM_CLASSES + c];
    }
}

__global__ void sdl_finalize_p(const unsigned int* __restrict__ partials,
                               float* __restrict__ out, int nblk) {
    // kernel boundary provides device-scope visibility of hist's stores
    __shared__ unsigned int psum[NCOUNT * 3];
    __shared__ float vals[NCOUNT];
    const int t = threadIdx.x;                      // 256 threads
    if (t < NCOUNT * 3) {                           // 3 chunks per counter
        int c = t / 3, j = t % 3;
        int chunk = (nblk + 2) / 3;
        int lo = j * chunk;
        int hi = lo + chunk; if (hi > nblk) hi = nblk;
        const unsigned int* __restrict__ row = partials + c * nblk;
        unsigned int v = 0;
        for (int i = lo; i < hi; ++i) v += row[i];
        psum[t] = v;
    }
    __syncthreads();
    if (t < NCOUNT) vals[t] = (float)(psum[t * 3] + psum[t * 3 + 1] + psum[t * 3 + 2]);
    __syncthreads();
    if (t == 0) {
        const float eps = 1e-5f;
        float s = 0.f;
        for (int c = 1; c < NUM_CLASSES; ++c) {
            float F = vals[c];
            float M = vals[NUM_CLASSES + c];
            float I = vals[2 * NUM_CLASSES + c];
            s += (2.f * I + eps) / (F + M + eps);
        }
        out[0] = 1.f - s / (float)(NUM_CLASSES - 1);
    }
}

// ---------- fallback path (tiny ws): proven R6 atomic scheme ----------
#define NREP 16
#define REPSTRIDE 80
#define GC_WORDS (NREP * REPSTRIDE)

__global__ void sdl_zero(unsigned int* __restrict__ c) {
    for (int i = threadIdx.x; i < GC_WORDS; i += TPB) c[i] = 0u;
}

__global__ __launch_bounds__(TPB, 2) void sdl_hist_a(
    const int4* __restrict__ f4, const int4* __restrict__ m4,
    unsigned int* __restrict__ gc, int n4, int nfull) {
    HIST_BODY

    unsigned int* rep = gc + (blockIdx.x & (NREP - 1)) * REPSTRIDE;
    const int t = threadIdx.x;
    if (t < NUM_CLASSES) {
        unsigned int v = 0;
        #pragma unroll
        for (int j = 0; j < NUM_CLASSES; ++j)
            v += h[t * NUM_CLASSES + j] + h[NBINS + t * NUM_CLASSES + j];
        if (v) atomicAdd(&rep[t], v);
    } else if (t >= 64 && t < 64 + NUM_CLASSES) {
        int c = t - 64;
        unsigned int v = 0;
        #pragma unroll
        for (int j = 0; j < NUM_CLASSES; ++j)
            v += h[j * NUM_CLASSES + c] + h[NBINS + j * NUM_CLASSES + c];
        if (v) atomicAdd(&rep[NUM_CLASSES + c], v);
    } else if (t >= 128 && t < 128 + NUM_CLASSES) {
        int c = t - 128;
        unsigned int v = h[c * NUM_CLASSES + c] + h[NBINS + c * NUM_CLASSES + c];
        if (v) atomicAdd(&rep[2 * NUM_CLASSES + c], v);
    }
}

__global__ void sdl_finalize_a(const unsigned int* __restrict__ gc,
                               float* __restrict__ out) {
    __shared__ float vals[NCOUNT];
    if (threadIdx.x < NCOUNT) {
        unsigned int v = 0;
        for (int r = 0; r < NREP; ++r) v += gc[r * REPSTRIDE + threadIdx.x];
        vals[threadIdx.x] = (float)v;
    }
    __syncthreads();
    if (threadIdx.x == 0) {
        const float eps = 1e-5f;
        float s = 0.f;
        for (int c = 1; c < NUM_CLASSES; ++c) {
            float F = vals[c];
            float M = vals[NUM_CLASSES + c];
            float I = vals[2 * NUM_CLASSES + c];
            s += (2.f * I + eps) / (F + M + eps);
        }
        out[0] = 1.f - s / (float)(NUM_CLASSES - 1);
    }
}

extern "C" void kernel_launch(void* const* d_in, const int* in_sizes, int n_in,
                              void* d_out, int out_size, void* d_ws, size_t ws_size,
                              hipStream_t stream) {
    const int* f = (const int*)d_in[0];
    const int* m = (const int*)d_in[1];
    float* out = (float*)d_out;

    int n  = in_sizes[0];         // 14,155,776 (divisible by 4)
    int n4 = n / 4;               // 3,538,944 int4-pairs

    int blocks = n4 / (TPB * 8);  // 1728: each thread exactly one 8-pair batch
    if (blocks < 1) blocks = 1;
    if (blocks > 4096) blocks = 4096;

    size_t need = (size_t)NCOUNT * blocks * sizeof(unsigned int);
    if (ws_size >= need) {
        // main path: 2 dispatches, no zeroing, no atomics
        unsigned int* partials = (unsigned int*)d_ws;
        int nthreads = blocks * TPB;
        int nfull = (n4 / (nthreads * 8)) * (nthreads * 8);
        sdl_hist_p<<<blocks, TPB, 0, stream>>>((const int4*)f, (const int4*)m,
                                               partials, blocks, n4, nfull);
        sdl_finalize_p<<<1, TPB, 0, stream>>>(partials, out, blocks);
    } else {
        // fallback: proven R6 atomic scheme (needs only 5 KB)
        unsigned int* gc = (unsigned int*)d_ws;
        int nthreads = blocks * TPB;
        int nfull = (n4 / (nthreads * 8)) * (nthreads * 8);
        sdl_zero<<<1, TPB, 0, stream>>>(gc);
        sdl_hist_a<<<blocks, TPB, 0, stream>>>((const int4*)f, (const int4*)m,
                                               gc, n4, nfull);
        sdl_finalize_a<<<1, 128, 0, stream>>>(gc, out);
    }
}

// Round 8
// 45.415 us; speedup vs baseline: 1.5152x; 1.5152x over previous
//
#include <hip/hip_runtime.h>

#define NUM_CLASSES 26
#define NBINS (NUM_CLASSES * NUM_CLASSES)   // 676 pair bins
#define SUBS 2                              // LDS sub-histograms (sub-major layout)
#define LDSN (SUBS * NBINS)                 // 1352 words = 5.4 KB
#define NCOUNT (3 * NUM_CLASSES)            // 78 logical counters
#define TPB 256

// ---------- shared inner loop ----------
// One ds_atomic per ELEMENT: pair bin idx = a*26 + b.
// F[c] = row sum, M[c] = col sum, I[c] = diagonal.
#define PROC_PAIR(aa, bb)                                                    \
    do {                                                                     \
        atomicAdd(&h[hb + ((aa).x * NUM_CLASSES + (bb).x)], 1u);             \
        atomicAdd(&h[hb + ((aa).y * NUM_CLASSES + (bb).y)], 1u);             \
        atomicAdd(&h[hb + ((aa).z * NUM_CLASSES + (bb).z)], 1u);             \
        atomicAdd(&h[hb + ((aa).w * NUM_CLASSES + (bb).w)], 1u);             \
    } while (0)

#define HIST_BODY                                                            \
    __shared__ unsigned int h[LDSN];                                         \
    for (int i = threadIdx.x; i < LDSN; i += TPB) h[i] = 0u;                 \
    __syncthreads();                                                         \
    const int tid      = blockIdx.x * TPB + threadIdx.x;                     \
    const int nthreads = gridDim.x * TPB;                                    \
    const int hb       = (threadIdx.x & (SUBS - 1)) * NBINS;                 \
    for (int base = tid; base < nfull; base += nthreads * 8) {               \
        int4 a[8], b[8];                                                     \
        _Pragma("unroll")                                                    \
        for (int k = 0; k < 8; ++k) a[k] = f4[base + k * nthreads];          \
        _Pragma("unroll")                                                    \
        for (int k = 0; k < 8; ++k) b[k] = m4[base + k * nthreads];          \
        _Pragma("unroll")                                                    \
        for (int k = 0; k < 8; ++k) {                                        \
            int4 aa = a[k], bb = b[k];                                       \
            PROC_PAIR(aa, bb);                                               \
        }                                                                    \
    }                                                                        \
    for (int i = nfull + tid; i < n4; i += nthreads) {                       \
        int4 aa = f4[i], bb = m4[i];                                         \
        PROC_PAIR(aa, bb);                                                   \
    }                                                                        \
    __syncthreads();

// ---------- main path: non-atomic per-block partials, 2 dispatches ----------
// partials layout: counter-major [78][nblk]; every word written unconditionally
// every call -> no zero pass needed, no RMW contention.
__global__ __launch_bounds__(TPB, 2) void sdl_hist_p(
    const int4* __restrict__ f4, const int4* __restrict__ m4,
    unsigned int* __restrict__ partials, int nblk, int n4, int nfull) {
    HIST_BODY

    const int t = threadIdx.x;
    const int b = blockIdx.x;
    if (t < NUM_CLASSES) {                         // wave 0: F[c] = row sum
        unsigned int v = 0;
        #pragma unroll
        for (int j = 0; j < NUM_CLASSES; ++j)
            v += h[t * NUM_CLASSES + j] + h[NBINS + t * NUM_CLASSES + j];
        partials[t * nblk + b] = v;
    } else if (t >= 64 && t < 64 + NUM_CLASSES) {  // wave 1: M[c] = col sum
        int c = t - 64;
        unsigned int v = 0;
        #pragma unroll
        for (int j = 0; j < NUM_CLASSES; ++j)
            v += h[j * NUM_CLASSES + c] + h[NBINS + j * NUM_CLASSES + c];
        partials[(NUM_CLASSES + c) * nblk + b] = v;
    } else if (t >= 128 && t < 128 + NUM_CLASSES) {  // wave 2: I[c] = diagonal
        int c = t - 128;
        partials[(2 * NUM_CLASSES + c) * nblk + b] =
            h[c * NUM_CLASSES + c] + h[NBINS + c * NUM_CLASSES + c];
    }
}

// Finalize with EXPLICIT MLP: uint4 loads in 8-deep batches (R7's scalar
// runtime-bound loop serialized to 1 load in flight -> 45.7 us).
__global__ void sdl_finalize_p(const unsigned int* __restrict__ partials,
                               float* __restrict__ out, int nblk) {
    __shared__ unsigned int psum[NCOUNT * 3];
    __shared__ float vals[NCOUNT];
    const int t = threadIdx.x;                      // 256 threads
    if (t < NCOUNT * 3) {                           // 3 threads per counter row
        const int c = t / 3, j = t % 3;
        const unsigned int* __restrict__ row = partials + (size_t)c * nblk;
        const uint4* __restrict__ row4 = (const uint4*)row;
        const int n4r = nblk >> 2;                  // int4s per row
        int chunk = (n4r + 2) / 3;
        int lo = j * chunk, hi = lo + chunk; if (hi > n4r) hi = n4r;
        unsigned int v = 0;
        int i = lo;
        for (; i + 8 <= hi; i += 8) {               // 8 x 16B in flight
            uint4 r[8];
            #pragma unroll
            for (int k = 0; k < 8; ++k) r[k] = row4[i + k];
            #pragma unroll
            for (int k = 0; k < 8; ++k) v += r[k].x + r[k].y + r[k].z + r[k].w;
        }
        for (; i < hi; ++i) { uint4 r = row4[i]; v += r.x + r.y + r.z + r.w; }
        if (j == 2)                                 // scalar row tail (nblk % 4)
            for (int w = n4r << 2; w < nblk; ++w) v += row[w];
        psum[t] = v;
    }
    __syncthreads();
    if (t < NCOUNT) vals[t] = (float)(psum[t * 3] + psum[t * 3 + 1] + psum[t * 3 + 2]);
    __syncthreads();
    if (t == 0) {
        const float eps = 1e-5f;
        float s = 0.f;
        for (int c = 1; c < NUM_CLASSES; ++c) {
            float F = vals[c];
            float M = vals[NUM_CLASSES + c];
            float I = vals[2 * NUM_CLASSES + c];
            s += (2.f * I + eps) / (F + M + eps);
        }
        out[0] = 1.f - s / (float)(NUM_CLASSES - 1);
    }
}

// ---------- fallback path (tiny ws): proven R6 atomic scheme ----------
#define NREP 16
#define REPSTRIDE 80
#define GC_WORDS (NREP * REPSTRIDE)

__global__ void sdl_zero(unsigned int* __restrict__ c) {
    for (int i = threadIdx.x; i < GC_WORDS; i += TPB) c[i] = 0u;
}

__global__ __launch_bounds__(TPB, 2) void sdl_hist_a(
    const int4* __restrict__ f4, const int4* __restrict__ m4,
    unsigned int* __restrict__ gc, int n4, int nfull) {
    HIST_BODY

    unsigned int* rep = gc + (blockIdx.x & (NREP - 1)) * REPSTRIDE;
    const int t = threadIdx.x;
    if (t < NUM_CLASSES) {
        unsigned int v = 0;
        #pragma unroll
        for (int j = 0; j < NUM_CLASSES; ++j)
            v += h[t * NUM_CLASSES + j] + h[NBINS + t * NUM_CLASSES + j];
        if (v) atomicAdd(&rep[t], v);
    } else if (t >= 64 && t < 64 + NUM_CLASSES) {
        int c = t - 64;
        unsigned int v = 0;
        #pragma unroll
        for (int j = 0; j < NUM_CLASSES; ++j)
            v += h[j * NUM_CLASSES + c] + h[NBINS + j * NUM_CLASSES + c];
        if (v) atomicAdd(&rep[NUM_CLASSES + c], v);
    } else if (t >= 128 && t < 128 + NUM_CLASSES) {
        int c = t - 128;
        unsigned int v = h[c * NUM_CLASSES + c] + h[NBINS + c * NUM_CLASSES + c];
        if (v) atomicAdd(&rep[2 * NUM_CLASSES + c], v);
    }
}

__global__ void sdl_finalize_a(const unsigned int* __restrict__ gc,
                               float* __restrict__ out) {
    __shared__ float vals[NCOUNT];
    if (threadIdx.x < NCOUNT) {
        unsigned int v = 0;
        for (int r = 0; r < NREP; ++r) v += gc[r * REPSTRIDE + threadIdx.x];
        vals[threadIdx.x] = (float)v;
    }
    __syncthreads();
    if (threadIdx.x == 0) {
        const float eps = 1e-5f;
        float s = 0.f;
        for (int c = 1; c < NUM_CLASSES; ++c) {
            float F = vals[c];
            float M = vals[NUM_CLASSES + c];
            float I = vals[2 * NUM_CLASSES + c];
            s += (2.f * I + eps) / (F + M + eps);
        }
        out[0] = 1.f - s / (float)(NUM_CLASSES - 1);
    }
}

extern "C" void kernel_launch(void* const* d_in, const int* in_sizes, int n_in,
                              void* d_out, int out_size, void* d_ws, size_t ws_size,
                              hipStream_t stream) {
    const int* f = (const int*)d_in[0];
    const int* m = (const int*)d_in[1];
    float* out = (float*)d_out;

    int n  = in_sizes[0];         // 14,155,776 (divisible by 4)
    int n4 = n / 4;               // 3,538,944 int4-pairs

    int blocks = n4 / (TPB * 8);  // 1728: each thread exactly one 8-pair batch
    if (blocks < 1) blocks = 1;
    if (blocks > 4096) blocks = 4096;

    size_t need = (size_t)NCOUNT * blocks * sizeof(unsigned int);
    if (ws_size >= need) {
        // main path: 2 dispatches, no zeroing, no atomics
        unsigned int* partials = (unsigned int*)d_ws;
        int nthreads = blocks * TPB;
        int nfull = (n4 / (nthreads * 8)) * (nthreads * 8);
        sdl_hist_p<<<blocks, TPB, 0, stream>>>((const int4*)f, (const int4*)m,
                                               partials, blocks, n4, nfull);
        sdl_finalize_p<<<1, TPB, 0, stream>>>(partials, out, blocks);
    } else {
        // fallback: proven R6 atomic scheme (needs only 5 KB)
        unsigned int* gc = (unsigned int*)d_ws;
        int nthreads = blocks * TPB;
        int nfull = (n4 / (nthreads * 8)) * (nthreads * 8);
        sdl_zero<<<1, TPB, 0, stream>>>(gc);
        sdl_hist_a<<<blocks, TPB, 0, stream>>>((const int4*)f, (const int4*)m,
                                               gc, n4, nfull);
        sdl_finalize_a<<<1, 128, 0, stream>>>(gc, out);
    }
}